// Round 1
// baseline (19812.753 us; speedup 1.0000x reference)
//
#include <hip/hip_runtime.h>
#include <hip/hip_bf16.h>

#define T_STEPS 1024
#define BATCH   64
#define DDIM    512
#define HDIM    512
#define NWG     64

typedef __attribute__((ext_vector_type(8))) short          bf16x8;
typedef __attribute__((ext_vector_type(4))) float          f32x4;
typedef __attribute__((ext_vector_type(8))) unsigned short u16x8;

static __device__ __forceinline__ unsigned short f2bf_bits(float f) {
    union { __hip_bfloat16 h; unsigned short u; } cv;
    cv.h = __float2bfloat16(f);
    return cv.u;
}

// ---------------------------------------------------------------------------
// P1: fold ln_g into weights, cast bf16, emit in MFMA B-fragment order.
// Block = (g, part): g = WG id (owns j in [8g,8g+8)), part = 0 (x rows) / 1 (h rows).
// Chunk layout: [g][part][tn][kstep][lane][e]  (e indexes k within lane; 8 contig)
//   k  = part*512 + kstep*32 + (lane>>4)*8 + e
//   c  = tn*16 + (lane&15);  n = (c>>3)*512 + g*8 + (c&7)
// ---------------------------------------------------------------------------
__global__ __launch_bounds__(256) void pack_weights(
    const float* __restrict__ Wf, const float* __restrict__ Wi,
    const float* __restrict__ Wg, const float* __restrict__ Wo,
    const float* __restrict__ ln_g, __hip_bfloat16* __restrict__ pack)
{
    __shared__ unsigned short tile[512 * 32];   // [k_local][c]
    const int blk = blockIdx.x;
    const int g = blk >> 1, part = blk & 1;
    const int tid = threadIdx.x;

    for (int idx = tid; idx < 512 * 32; idx += 256) {
        int kl = idx >> 5, c = idx & 31;
        int q = c >> 3, jl = c & 7;
        int k = part * 512 + kl;
        const float* W = (q == 0) ? Wf : ((q == 1) ? Wi : ((q == 2) ? Wg : Wo));
        float v = W[k * 512 + g * 8 + jl] * ln_g[k];
        tile[kl * 32 + c] = f2bf_bits(v);
    }
    __syncthreads();

    unsigned short* out = (unsigned short*)(pack + (size_t)blk * 16384);
    for (int s = tid; s < 2048; s += 256) {        // slot = tn*1024 + ks*64 + l
        int tn = s >> 10, ks = (s >> 6) & 15, l = s & 63;
        u16x8 v;
#pragma unroll
        for (int e = 0; e < 8; ++e) {
            int klocal = ks * 32 + ((l >> 4) * 8) + e;
            int c = tn * 16 + (l & 15);
            v[e] = tile[klocal * 32 + c];
        }
        *(u16x8*)(out + (size_t)s * 8) = v;
    }
}

// ---------------------------------------------------------------------------
// P2: S[n] = sum_k ln_g[k]*W[k,n],  C[n] = sum_k ln_b[k]*W[k,n] + bias[n]
// ---------------------------------------------------------------------------
__global__ __launch_bounds__(256) void compute_sc(
    const float* __restrict__ Wf, const float* __restrict__ Wi,
    const float* __restrict__ Wg, const float* __restrict__ Wo,
    const float* __restrict__ bf_, const float* __restrict__ bi_,
    const float* __restrict__ bg_, const float* __restrict__ bo_,
    const float* __restrict__ ln_g, const float* __restrict__ ln_b,
    float* __restrict__ S, float* __restrict__ C)
{
    int n = blockIdx.x * 256 + threadIdx.x;        // 0..2047
    int q = n >> 9, j = n & 511;
    const float* W = (q == 0) ? Wf : ((q == 1) ? Wi : ((q == 2) ? Wg : Wo));
    const float* bb = (q == 0) ? bf_ : ((q == 1) ? bi_ : ((q == 2) ? bg_ : bo_));
    float accS = 0.f, accC = 0.f;
    for (int k = 0; k < 1024; ++k) {
        float w = W[k * 512 + j];
        accS += ln_g[k] * w;
        accC += ln_b[k] * w;
    }
    S[n] = accS;
    C[n] = accC + bb[j];
}

// ---------------------------------------------------------------------------
// P3: x -> bf16 copy + per-row sum / sumsq (fp32). One wave per (t,b) row.
// ---------------------------------------------------------------------------
__global__ __launch_bounds__(256) void prep_x(
    const float* __restrict__ x, __hip_bfloat16* __restrict__ xb,
    float* __restrict__ sx, float* __restrict__ sq)
{
    const int wave = threadIdx.x >> 6, lane = threadIdx.x & 63;
    const long row = (long)blockIdx.x * 4 + wave;  // 0..65535
    const float* src = x + row * 512 + lane * 8;
    float4 a = *(const float4*)src;
    float4 b = *(const float4*)(src + 4);
    float vals[8] = {a.x, a.y, a.z, a.w, b.x, b.y, b.z, b.w};
    u16x8 o;
    float s = 0.f, qq = 0.f;
#pragma unroll
    for (int e = 0; e < 8; ++e) {
        s += vals[e];
        qq += vals[e] * vals[e];
        o[e] = f2bf_bits(vals[e]);
    }
    *(u16x8*)((unsigned short*)xb + row * 512 + lane * 8) = o;
#pragma unroll
    for (int d = 1; d < 64; d <<= 1) {
        s  += __shfl_xor(s, d);
        qq += __shfl_xor(qq, d);
    }
    if (lane == 0) { sx[row] = s; sq[row] = qq; }
}

// ---------------------------------------------------------------------------
// Main persistent kernel: 64 WGs x 512 threads, grid barrier per timestep.
// Wave w: m = w&3 (16-row M tile), part = w>>2 (0: x-GEMM, 1: h-GEMM).
// Thread t: b = t>>3, jl = t&7 owns gate/state element (b, 8g+jl).
// ---------------------------------------------------------------------------
__global__ __launch_bounds__(512, 2) void qlstm_main(
    const float* __restrict__ x,
    const __hip_bfloat16* __restrict__ pack,
    const float* __restrict__ Sarr, const float* __restrict__ Carr,
    const __hip_bfloat16* __restrict__ xb,
    const float* __restrict__ sx, const float* __restrict__ sq,
    __hip_bfloat16* __restrict__ hxb,     // [2][64][512] bf16, double buffer
    float* __restrict__ psum,             // [2][64][64] fp32 partial sums
    float* __restrict__ psq,              // [2][64][64] fp32 partial sumsq
    unsigned int* __restrict__ cnt,       // epoch barrier counter (zeroed)
    float* __restrict__ out)              // stacked | hx | cx (fp32)
{
    const int g = blockIdx.x;
    const int tid = threadIdx.x;
    const int wave = tid >> 6, lane = tid & 63;
    const int m = wave & 3, part = wave >> 2;
    const int b = tid >> 3, jl = tid & 7, jg = g * 8 + jl;

    __shared__ float zX[64 * 33], zH[64 * 33];
    __shared__ float sps[64 * 8], spq[64 * 8];
    __shared__ float sxl[64], sql[64];
    __shared__ float Scol[32], Ccol[32];

    if (tid < 32) {
        int n = (tid >> 3) * 512 + g * 8 + (tid & 7);
        Scol[tid] = Sarr[n];
        Ccol[tid] = Carr[n];
    }

    // Persistent B-fragments: 2 N-tiles x 16 k-steps x 8 bf16 = 128 VGPRs.
    bf16x8 Bf0[16], Bf1[16];
    {
        const bf16x8* pb = (const bf16x8*)(pack + (size_t)(g * 2 + part) * 16384);
#pragma unroll
        for (int ks = 0; ks < 16; ++ks) {
            Bf0[ks] = pb[ks * 64 + lane];
            Bf1[ks] = pb[1024 + ks * 64 + lane];
        }
    }

    const int arow = m * 16 + (lane & 15);
    const int acol = (lane >> 4) * 8;
    float cx = 0.f;

    for (int t = 0; t < T_STEPS; ++t) {
        const int p = t & 1;

        // ---- grid barrier (epoch counter, release/acquire) ----
        __threadfence();
        __syncthreads();
        if (tid == 0) {
            unsigned prev = __hip_atomic_fetch_add(cnt, 1u, __ATOMIC_RELEASE,
                                                   __HIP_MEMORY_SCOPE_AGENT);
            unsigned want = (unsigned)(t + 1) * NWG;
            if (prev + 1u != want) {
                while (__hip_atomic_load(cnt, __ATOMIC_RELAXED,
                                         __HIP_MEMORY_SCOPE_AGENT) < want) {}
            }
            __threadfence();
        }
        __syncthreads();

        // ---- phase A: stats partial reduce + residual load (overlaps GEMM) ----
        float xres = x[(size_t)t * 32768 + b * 512 + jg];
        {
            const float4* p0 = (const float4*)(psum + (size_t)p * 4096 + b * 64 + jl * 8);
            const float4* p1 = (const float4*)(psq + (size_t)p * 4096 + b * 64 + jl * 8);
            float4 a0 = p0[0], a1 = p0[1], c0 = p1[0], c1 = p1[1];
            sps[b * 8 + jl] = a0.x + a0.y + a0.z + a0.w + a1.x + a1.y + a1.z + a1.w;
            spq[b * 8 + jl] = c0.x + c0.y + c0.z + c0.w + c1.x + c1.y + c1.z + c1.w;
            if (jl == 0) sxl[b] = sx[t * 64 + b];
            if (jl == 1) sql[b] = sq[t * 64 + b];
        }

        // ---- GEMM: acc += A(comb part) * B(frags) ----
        f32x4 acc0 = {0.f, 0.f, 0.f, 0.f}, acc1 = {0.f, 0.f, 0.f, 0.f};
        {
            const __hip_bfloat16* Ab =
                part ? (hxb + (size_t)p * 32768) : (xb + (size_t)t * 32768);
            const bf16x8* Ap = (const bf16x8*)(Ab + arow * 512 + acol);
#pragma unroll
            for (int ks = 0; ks < 16; ++ks) {
                bf16x8 a = Ap[ks * 4];
                acc0 = __builtin_amdgcn_mfma_f32_16x16x32_bf16(a, Bf0[ks], acc0, 0, 0, 0);
                acc1 = __builtin_amdgcn_mfma_f32_16x16x32_bf16(a, Bf1[ks], acc1, 0, 0, 0);
            }
        }
        {
            float* zb = part ? zH : zX;
            int r0 = m * 16 + (lane >> 4) * 4, col = lane & 15;
#pragma unroll
            for (int r = 0; r < 4; ++r) {
                zb[(r0 + r) * 33 + col]      = acc0[r];
                zb[(r0 + r) * 33 + 16 + col] = acc1[r];
            }
        }
        __syncthreads();

        // ---- gates / state update (one thread per (b, j)) ----
        {
            float hs = 0.f, hq = 0.f;
#pragma unroll
            for (int c = 0; c < 8; ++c) { hs += sps[b * 8 + c]; hq += spq[b * 8 + c]; }
            float mu = (sxl[b] + hs) * (1.f / 1024.f);
            float var = (sql[b] + hq) * (1.f / 1024.f) - mu * mu;
            float rs = rsqrtf(var + 1e-5f);

            float zf = zX[b * 33 + jl]      + zH[b * 33 + jl];
            float zi = zX[b * 33 + 8 + jl]  + zH[b * 33 + 8 + jl];
            float zg = zX[b * 33 + 16 + jl] + zH[b * 33 + 16 + jl];
            float zo = zX[b * 33 + 24 + jl] + zH[b * 33 + 24 + jl];
            zf = rs * (zf - mu * Scol[jl])      + Ccol[jl];
            zi = rs * (zi - mu * Scol[8 + jl])  + Ccol[8 + jl];
            zg = rs * (zg - mu * Scol[16 + jl]) + Ccol[16 + jl];
            zo = rs * (zo - mu * Scol[24 + jl]) + Ccol[24 + jl];

            float f  = 1.f / (1.f + __expf(-zf));
            float i_ = 1.f / (1.f + __expf(-zi));
            float gg = 2.f / (1.f + __expf(-2.f * zg)) - 1.f;
            float o_ = 1.f / (1.f + __expf(-zo));
            cx = f * cx + i_ * gg;
            float th = 2.f / (1.f + __expf(-2.f * cx)) - 1.f;
            float hval = o_ * th + xres;

            out[(size_t)t * 32768 + b * 512 + jg] = hval;
            hxb[(size_t)(p ^ 1) * 32768 + b * 512 + jg] = __float2bfloat16(hval);

            float s1 = hval, s2 = hval * hval;
            s1 += __shfl_xor(s1, 1, 8); s2 += __shfl_xor(s2, 1, 8);
            s1 += __shfl_xor(s1, 2, 8); s2 += __shfl_xor(s2, 2, 8);
            s1 += __shfl_xor(s1, 4, 8); s2 += __shfl_xor(s2, 4, 8);
            if (jl == 0) {
                psum[(size_t)(p ^ 1) * 4096 + b * 64 + g] = s1;
                psq [(size_t)(p ^ 1) * 4096 + b * 64 + g] = s2;
            }
            if (t == T_STEPS - 1) {
                out[(size_t)T_STEPS * 32768 + b * 512 + jg] = hval;
                out[(size_t)T_STEPS * 32768 + 32768 + b * 512 + jg] = cx;
            }
        }
    }
}

// ---------------------------------------------------------------------------
extern "C" void kernel_launch(void* const* d_in, const int* in_sizes, int n_in,
                              void* d_out, int out_size, void* d_ws, size_t ws_size,
                              hipStream_t stream)
{
    const float* x    = (const float*)d_in[0];
    const float* ln_g = (const float*)d_in[1];
    const float* ln_b = (const float*)d_in[2];
    const float* Wf   = (const float*)d_in[3];
    const float* bf_  = (const float*)d_in[4];
    const float* Wi   = (const float*)d_in[5];
    const float* bi_  = (const float*)d_in[6];
    const float* Wg   = (const float*)d_in[7];
    const float* bg_  = (const float*)d_in[8];
    const float* Wo   = (const float*)d_in[9];
    const float* bo_  = (const float*)d_in[10];

    char* ws = (char*)d_ws;
    size_t off = 0;
    auto take = [&](size_t bytes) -> char* {
        char* p = ws + off;
        off += (bytes + 255) & ~(size_t)255;
        return p;
    };
    __hip_bfloat16* pack = (__hip_bfloat16*)take((size_t)2097152 * 2); // 4 MB
    float* S             = (float*)take(2048 * 4);
    float* C             = (float*)take(2048 * 4);
    __hip_bfloat16* xb   = (__hip_bfloat16*)take((size_t)33554432 * 2); // 64 MB
    float* sx            = (float*)take(65536 * 4);
    float* sq            = (float*)take(65536 * 4);
    char* ctrl = ws + off;
    __hip_bfloat16* hxb  = (__hip_bfloat16*)take((size_t)2 * BATCH * HDIM * 2);
    float* psum          = (float*)take((size_t)2 * 4096 * 4);
    float* psq           = (float*)take((size_t)2 * 4096 * 4);
    unsigned int* cnt    = (unsigned int*)take(256);
    size_t ctrl_bytes = (size_t)((ws + off) - ctrl);

    hipMemsetAsync(ctrl, 0, ctrl_bytes, stream);
    pack_weights<<<dim3(128), dim3(256), 0, stream>>>(Wf, Wi, Wg, Wo, ln_g, pack);
    compute_sc<<<dim3(8), dim3(256), 0, stream>>>(Wf, Wi, Wg, Wo, bf_, bi_, bg_, bo_,
                                                  ln_g, ln_b, S, C);
    prep_x<<<dim3(16384), dim3(256), 0, stream>>>(x, xb, sx, sq);
    qlstm_main<<<dim3(NWG), dim3(512), 0, stream>>>(x, pack, S, C, xb, sx, sq,
                                                    hxb, psum, psq, cnt, (float*)d_out);
}

// Round 2
// 10288.931 us; speedup vs baseline: 1.9256x; 1.9256x over previous
//
#include <hip/hip_runtime.h>
#include <hip/hip_bf16.h>

#define T_STEPS 1024
#define NWG     64

typedef __attribute__((ext_vector_type(8))) short          bf16x8;
typedef __attribute__((ext_vector_type(4))) float          f32x4;
typedef __attribute__((ext_vector_type(8))) unsigned short u16x8;

static __device__ __forceinline__ unsigned short f2bf_bits(float f) {
    union { __hip_bfloat16 h; unsigned short u; } cv;
    cv.h = __float2bfloat16(f);
    return cv.u;
}

// ---------------------------------------------------------------------------
// P1: fold ln_g into weights, cast bf16, emit in MFMA B-fragment order.
// Chunk layout: [g][part][tn][kstep][lane][e]
//   k  = part*512 + kstep*32 + (lane>>4)*8 + e
//   c  = tn*16 + (lane&15);  n = (c>>3)*512 + g*8 + (c&7)
// ---------------------------------------------------------------------------
__global__ __launch_bounds__(256) void pack_weights(
    const float* __restrict__ Wf, const float* __restrict__ Wi,
    const float* __restrict__ Wg, const float* __restrict__ Wo,
    const float* __restrict__ ln_g, __hip_bfloat16* __restrict__ pack)
{
    __shared__ unsigned short tile[512 * 32];   // [k_local][c]
    const int blk = blockIdx.x;
    const int g = blk >> 1, part = blk & 1;
    const int tid = threadIdx.x;

    for (int idx = tid; idx < 512 * 32; idx += 256) {
        int kl = idx >> 5, c = idx & 31;
        int q = c >> 3, jl = c & 7;
        int k = part * 512 + kl;
        const float* W = (q == 0) ? Wf : ((q == 1) ? Wi : ((q == 2) ? Wg : Wo));
        float v = W[k * 512 + g * 8 + jl] * ln_g[k];
        tile[kl * 32 + c] = f2bf_bits(v);
    }
    __syncthreads();

    unsigned short* out = (unsigned short*)(pack + (size_t)blk * 16384);
    for (int s = tid; s < 2048; s += 256) {        // slot = tn*1024 + ks*64 + l
        int tn = s >> 10, ks = (s >> 6) & 15, l = s & 63;
        u16x8 v;
#pragma unroll
        for (int e = 0; e < 8; ++e) {
            int klocal = ks * 32 + ((l >> 4) * 8) + e;
            int c = tn * 16 + (l & 15);
            v[e] = tile[klocal * 32 + c];
        }
        *(u16x8*)(out + (size_t)s * 8) = v;
    }
}

// ---------------------------------------------------------------------------
// P2: S[n] = sum_k ln_g[k]*W[k,n],  C[n] = sum_k ln_b[k]*W[k,n] + bias[n]
// ---------------------------------------------------------------------------
__global__ __launch_bounds__(256) void compute_sc(
    const float* __restrict__ Wf, const float* __restrict__ Wi,
    const float* __restrict__ Wg, const float* __restrict__ Wo,
    const float* __restrict__ bf_, const float* __restrict__ bi_,
    const float* __restrict__ bg_, const float* __restrict__ bo_,
    const float* __restrict__ ln_g, const float* __restrict__ ln_b,
    float* __restrict__ S, float* __restrict__ C)
{
    int n = blockIdx.x * 256 + threadIdx.x;        // 0..2047
    int q = n >> 9, j = n & 511;
    const float* W = (q == 0) ? Wf : ((q == 1) ? Wi : ((q == 2) ? Wg : Wo));
    const float* bb = (q == 0) ? bf_ : ((q == 1) ? bi_ : ((q == 2) ? bg_ : bo_));
    float accS = 0.f, accC = 0.f;
    for (int k = 0; k < 1024; ++k) {
        float w = W[k * 512 + j];
        accS += ln_g[k] * w;
        accC += ln_b[k] * w;
    }
    S[n] = accS;
    C[n] = accC + bb[j];
}

// ---------------------------------------------------------------------------
// P3: x -> bf16 copy + per-row sum / sumsq (fp32). One wave per (t,b) row.
// ---------------------------------------------------------------------------
__global__ __launch_bounds__(256) void prep_x(
    const float* __restrict__ x, __hip_bfloat16* __restrict__ xb,
    float* __restrict__ sx, float* __restrict__ sq)
{
    const int wave = threadIdx.x >> 6, lane = threadIdx.x & 63;
    const long row = (long)blockIdx.x * 4 + wave;  // 0..65535
    const float* src = x + row * 512 + lane * 8;
    float4 a = *(const float4*)src;
    float4 b = *(const float4*)(src + 4);
    float vals[8] = {a.x, a.y, a.z, a.w, b.x, b.y, b.z, b.w};
    u16x8 o;
    float s = 0.f, qq = 0.f;
#pragma unroll
    for (int e = 0; e < 8; ++e) {
        s += vals[e];
        qq += vals[e] * vals[e];
        o[e] = f2bf_bits(vals[e]);
    }
    *(u16x8*)((unsigned short*)xb + row * 512 + lane * 8) = o;
#pragma unroll
    for (int d = 1; d < 64; d <<= 1) {
        s  += __shfl_xor(s, d);
        qq += __shfl_xor(qq, d);
    }
    if (lane == 0) { sx[row] = s; sq[row] = qq; }
}

// ---------------------------------------------------------------------------
// Main persistent kernel: 64 WGs x 512 threads.
// Per-step sync: per-WG flags (release store) + all-wave spin on 64 flags.
// Coherent (agent-scope) loads for h/psum; NO threadfence -> L2 stays warm.
// Wave w: m = w&3 (16-row M tile), kh = w>>2 (K half). All waves do BOTH
// the h-GEMM (critical) and next-step x-GEMM (off critical path).
// Thread t: b = t>>3, jl = t&7 owns gate/state element (b, 8g+jl).
// ---------------------------------------------------------------------------
__global__ __launch_bounds__(512, 2) void qlstm_main(
    const float* __restrict__ x,
    const __hip_bfloat16* __restrict__ pack,
    const float* __restrict__ Sarr, const float* __restrict__ Carr,
    const __hip_bfloat16* __restrict__ xb,
    const float* __restrict__ sx, const float* __restrict__ sq,
    __hip_bfloat16* __restrict__ hxb,     // [2][64][512] bf16 (zeroed)
    float2* __restrict__ psc,             // [2][64][64] float2 (zeroed)
    unsigned int* __restrict__ flags,     // [64] spaced 16 u32 (zeroed)
    float* __restrict__ out)              // stacked | hx | cx (fp32)
{
    const int g = blockIdx.x;
    const int tid = threadIdx.x;
    const int wave = tid >> 6, lane = tid & 63;
    const int m = wave & 3, kh = wave >> 2;
    const int b = tid >> 3, jl = tid & 7, jg = g * 8 + jl;

    __shared__ float zXs[2][2][2112];          // [parity][kh][row*33+col]
    __shared__ float zHs[2][2112];             // [kh]
    __shared__ float sps[512], spq[512];
    __shared__ float sxl[64], sql[64];
    __shared__ float2 pls[64];
    __shared__ __align__(16) unsigned short hsl[64][8];
    __shared__ float Scol[32], Ccol[32];

    if (tid < 32) {
        int n = (tid >> 3) * 512 + g * 8 + (tid & 7);
        Scol[tid] = Sarr[n];
        Ccol[tid] = Carr[n];
    }

    // Persistent B-fragments: 4 x 8 frags x 4 VGPR = 128 VGPRs.
    bf16x8 Bx0[8], Bx1[8], Bh0[8], Bh1[8];
    {
        const bf16x8* px = (const bf16x8*)(pack + (size_t)(g * 2 + 0) * 16384);
        const bf16x8* ph = (const bf16x8*)(pack + (size_t)(g * 2 + 1) * 16384);
#pragma unroll
        for (int i = 0; i < 8; ++i) {
            int ksp = kh * 8 + i;
            Bx0[i] = px[ksp * 64 + lane];
            Bx1[i] = px[1024 + ksp * 64 + lane];
            Bh0[i] = ph[ksp * 64 + lane];
            Bh1[i] = ph[1024 + ksp * 64 + lane];
        }
    }

    const int arow = m * 16 + (lane & 15);
    const int acol = (lane >> 4) * 8;
    const int r0 = m * 16 + (lane >> 4) * 4, c0 = lane & 15;
    float cx = 0.f;

    // zX for t=0 (x-part GEMM, recurrence-independent)
    {
        const bf16x8* Ap = (const bf16x8*)(xb + (size_t)arow * 512 + kh * 256 + acol);
        bf16x8 afr[8];
#pragma unroll
        for (int ks = 0; ks < 8; ++ks) afr[ks] = Ap[ks * 4];
        f32x4 a0 = {0.f, 0.f, 0.f, 0.f}, a1 = {0.f, 0.f, 0.f, 0.f};
#pragma unroll
        for (int ks = 0; ks < 8; ++ks) {
            a0 = __builtin_amdgcn_mfma_f32_16x16x32_bf16(afr[ks], Bx0[ks], a0, 0, 0, 0);
            a1 = __builtin_amdgcn_mfma_f32_16x16x32_bf16(afr[ks], Bx1[ks], a1, 0, 0, 0);
        }
        float* zb = &zXs[0][kh][0];
#pragma unroll
        for (int r = 0; r < 4; ++r) {
            zb[(r0 + r) * 33 + c0]      = a0[r];
            zb[(r0 + r) * 33 + 16 + c0] = a1[r];
        }
    }

    for (int t = 0; t < T_STEPS; ++t) {
        const int p = t & 1;

        // issue recurrence-independent loads before spinning
        float xres = x[(size_t)t * 32768 + b * 512 + jg];
        float sxv = 0.f, sqv = 0.f;
        if (tid < 64) { sxv = sx[t * 64 + tid]; sqv = sq[t * 64 + tid]; }

        // ---- spin: all waves poll the 64 per-WG flags (coherent loads) ----
        {
            const unsigned int* fp_ = flags + (lane << 4);
            for (;;) {
                unsigned f = __hip_atomic_load(fp_, __ATOMIC_RELAXED,
                                               __HIP_MEMORY_SCOPE_AGENT);
                if (__all((int)f >= t)) break;
            }
            asm volatile("" ::: "memory");
        }

        // ---- issue coherent h A-frag loads (16 x 8B per lane) ----
        unsigned long long hlo[8], hhi[8];
        {
            const unsigned long long* hp =
                (const unsigned long long*)(hxb + (size_t)p * 32768);
            const int ebase = (arow * 512 + kh * 256 + acol) >> 2;
#pragma unroll
            for (int ks = 0; ks < 8; ++ks) {
                hlo[ks] = __hip_atomic_load(hp + ebase + ks * 8, __ATOMIC_RELAXED,
                                            __HIP_MEMORY_SCOPE_AGENT);
                hhi[ks] = __hip_atomic_load(hp + ebase + ks * 8 + 1, __ATOMIC_RELAXED,
                                            __HIP_MEMORY_SCOPE_AGENT);
            }
        }

        // ---- stats partial reduce (coherent psum loads, overlap h loads) ----
        {
            const unsigned long long* pp =
                (const unsigned long long*)(psc + (size_t)p * 4096 + b * 64 + jl * 8);
            float s1 = 0.f, s2 = 0.f;
#pragma unroll
            for (int j = 0; j < 8; ++j) {
                unsigned long long v = __hip_atomic_load(pp + j, __ATOMIC_RELAXED,
                                                         __HIP_MEMORY_SCOPE_AGENT);
                union { unsigned long long u; float2 f; } cv; cv.u = v;
                s1 += cv.f.x; s2 += cv.f.y;
            }
            sps[tid] = s1; spq[tid] = s2;
        }
        if (tid < 64) { sxl[tid] = sxv; sql[tid] = sqv; }

        // ---- h-GEMM (critical path): 16 MFMA per wave ----
        {
            f32x4 h0 = {0.f, 0.f, 0.f, 0.f}, h1 = {0.f, 0.f, 0.f, 0.f};
#pragma unroll
            for (int ks = 0; ks < 8; ++ks) {
                union { unsigned long long u[2]; bf16x8 v; } cv;
                cv.u[0] = hlo[ks]; cv.u[1] = hhi[ks];
                h0 = __builtin_amdgcn_mfma_f32_16x16x32_bf16(cv.v, Bh0[ks], h0, 0, 0, 0);
                h1 = __builtin_amdgcn_mfma_f32_16x16x32_bf16(cv.v, Bh1[ks], h1, 0, 0, 0);
            }
            float* zb = &zHs[kh][0];
#pragma unroll
            for (int r = 0; r < 4; ++r) {
                zb[(r0 + r) * 33 + c0]      = h0[r];
                zb[(r0 + r) * 33 + 16 + c0] = h1[r];
            }
        }
        __syncthreads();

        // ---- gates / state update (thread owns (b, jg)) ----
        {
            float hs = 0.f, hq = 0.f;
#pragma unroll
            for (int c = 0; c < 8; ++c) { hs += sps[b * 8 + c]; hq += spq[b * 8 + c]; }
            float mu = (sxl[b] + hs) * (1.f / 1024.f);
            float var = (sql[b] + hq) * (1.f / 1024.f) - mu * mu;
            float rs = rsqrtf(var + 1e-5f);

            const float* zx0 = &zXs[p][0][0];
            const float* zx1 = &zXs[p][1][0];
            const float* zh0 = &zHs[0][0];
            const float* zh1 = &zHs[1][0];
            const int i0 = b * 33;
            float zf = zx0[i0 + jl]      + zx1[i0 + jl]      + zh0[i0 + jl]      + zh1[i0 + jl];
            float zi = zx0[i0 + 8 + jl]  + zx1[i0 + 8 + jl]  + zh0[i0 + 8 + jl]  + zh1[i0 + 8 + jl];
            float zg = zx0[i0 + 16 + jl] + zx1[i0 + 16 + jl] + zh0[i0 + 16 + jl] + zh1[i0 + 16 + jl];
            float zo = zx0[i0 + 24 + jl] + zx1[i0 + 24 + jl] + zh0[i0 + 24 + jl] + zh1[i0 + 24 + jl];
            zf = rs * (zf - mu * Scol[jl])      + Ccol[jl];
            zi = rs * (zi - mu * Scol[8 + jl])  + Ccol[8 + jl];
            zg = rs * (zg - mu * Scol[16 + jl]) + Ccol[16 + jl];
            zo = rs * (zo - mu * Scol[24 + jl]) + Ccol[24 + jl];

            float f  = 1.f / (1.f + __expf(-zf));
            float i_ = 1.f / (1.f + __expf(-zi));
            float gg = 2.f / (1.f + __expf(-2.f * zg)) - 1.f;
            float o_ = 1.f / (1.f + __expf(-zo));
            cx = f * cx + i_ * gg;
            float th = 2.f / (1.f + __expf(-2.f * cx)) - 1.f;
            float hval = o_ * th + xres;

            out[(size_t)t * 32768 + b * 512 + jg] = hval;
            hsl[b][jl] = f2bf_bits(hval);

            float s1 = hval, s2 = hval * hval;
            s1 += __shfl_xor(s1, 1, 8); s2 += __shfl_xor(s2, 1, 8);
            s1 += __shfl_xor(s1, 2, 8); s2 += __shfl_xor(s2, 2, 8);
            s1 += __shfl_xor(s1, 4, 8); s2 += __shfl_xor(s2, 4, 8);
            if (jl == 0) pls[b] = make_float2(s1, s2);

            if (t == T_STEPS - 1) {
                out[(size_t)T_STEPS * 32768 + b * 512 + jg] = hval;
                out[(size_t)T_STEPS * 32768 + 32768 + b * 512 + jg] = cx;
            }
        }
        __syncthreads();

        if (t + 1 < T_STEPS) {
            // ---- publish h slice + psums (wave0 plain stores),
            //      then release-store flag (flushes via wbl2) ----
            if (wave == 0) {
                u16x8 hv = *(const u16x8*)&hsl[lane][0];
                *(u16x8*)((unsigned short*)hxb + (size_t)(p ^ 1) * 32768
                          + lane * 512 + g * 8) = hv;
                psc[(size_t)(p ^ 1) * 4096 + lane * 64 + g] = pls[lane];
                if (lane == 0) {
                    __hip_atomic_store(flags + (g << 4), (unsigned)(t + 1),
                                       __ATOMIC_RELEASE, __HIP_MEMORY_SCOPE_AGENT);
                }
            }

            // ---- x-GEMM for t+1 (off critical path, overlaps the wait) ----
            const bf16x8* Ap = (const bf16x8*)(xb + (size_t)(t + 1) * 32768
                                               + arow * 512 + kh * 256 + acol);
            bf16x8 afr[8];
#pragma unroll
            for (int ks = 0; ks < 8; ++ks) afr[ks] = Ap[ks * 4];
            f32x4 a0 = {0.f, 0.f, 0.f, 0.f}, a1 = {0.f, 0.f, 0.f, 0.f};
#pragma unroll
            for (int ks = 0; ks < 8; ++ks) {
                a0 = __builtin_amdgcn_mfma_f32_16x16x32_bf16(afr[ks], Bx0[ks], a0, 0, 0, 0);
                a1 = __builtin_amdgcn_mfma_f32_16x16x32_bf16(afr[ks], Bx1[ks], a1, 0, 0, 0);
            }
            float* zb = &zXs[p ^ 1][kh][0];
#pragma unroll
            for (int r = 0; r < 4; ++r) {
                zb[(r0 + r) * 33 + c0]      = a0[r];
                zb[(r0 + r) * 33 + 16 + c0] = a1[r];
            }
        }
    }
}

// ---------------------------------------------------------------------------
extern "C" void kernel_launch(void* const* d_in, const int* in_sizes, int n_in,
                              void* d_out, int out_size, void* d_ws, size_t ws_size,
                              hipStream_t stream)
{
    const float* x    = (const float*)d_in[0];
    const float* ln_g = (const float*)d_in[1];
    const float* ln_b = (const float*)d_in[2];
    const float* Wf   = (const float*)d_in[3];
    const float* bf_  = (const float*)d_in[4];
    const float* Wi   = (const float*)d_in[5];
    const float* bi_  = (const float*)d_in[6];
    const float* Wg   = (const float*)d_in[7];
    const float* bg_  = (const float*)d_in[8];
    const float* Wo   = (const float*)d_in[9];
    const float* bo_  = (const float*)d_in[10];

    char* ws = (char*)d_ws;
    size_t off = 0;
    auto take = [&](size_t bytes) -> char* {
        char* p = ws + off;
        off += (bytes + 255) & ~(size_t)255;
        return p;
    };
    __hip_bfloat16* pack = (__hip_bfloat16*)take((size_t)2097152 * 2); // 4 MB
    float* S             = (float*)take(2048 * 4);
    float* C             = (float*)take(2048 * 4);
    __hip_bfloat16* xb   = (__hip_bfloat16*)take((size_t)33554432 * 2); // 64 MB
    float* sx            = (float*)take(65536 * 4);
    float* sq            = (float*)take(65536 * 4);
    char* ctrl = ws + off;
    __hip_bfloat16* hxb  = (__hip_bfloat16*)take((size_t)2 * 64 * 512 * 2);
    float2* psc          = (float2*)take((size_t)2 * 64 * 64 * 8);
    unsigned int* flags  = (unsigned int*)take(64 * 16 * 4);
    size_t ctrl_bytes = (size_t)((ws + off) - ctrl);

    hipMemsetAsync(ctrl, 0, ctrl_bytes, stream);
    pack_weights<<<dim3(128), dim3(256), 0, stream>>>(Wf, Wi, Wg, Wo, ln_g, pack);
    compute_sc<<<dim3(8), dim3(256), 0, stream>>>(Wf, Wi, Wg, Wo, bf_, bi_, bg_, bo_,
                                                  ln_g, ln_b, S, C);
    prep_x<<<dim3(16384), dim3(256), 0, stream>>>(x, xb, sx, sq);
    qlstm_main<<<dim3(NWG), dim3(512), 0, stream>>>(x, pack, S, C, xb, sx, sq,
                                                    hxb, psc, flags, (float*)d_out);
}

// Round 3
// 9008.291 us; speedup vs baseline: 2.1994x; 1.1422x over previous
//
#include <hip/hip_runtime.h>
#include <hip/hip_bf16.h>

#define T_STEPS 1024
#define NWG     64

typedef __attribute__((ext_vector_type(8))) short          bf16x8;
typedef __attribute__((ext_vector_type(4))) float          f32x4;
typedef __attribute__((ext_vector_type(8))) unsigned short u16x8;

static __device__ __forceinline__ unsigned short f2bf_bits(float f) {
    union { __hip_bfloat16 h; unsigned short u; } cv;
    cv.h = __float2bfloat16(f);
    return cv.u;
}

// ---------------------------------------------------------------------------
// P1: fold ln_g into weights, cast bf16, emit in MFMA B-fragment order.
// Chunk layout: [g][part][tn][kstep][lane][e]
//   k  = part*512 + kstep*32 + (lane>>4)*8 + e
//   c  = tn*16 + (lane&15);  n = (c>>3)*512 + g*8 + (c&7)
// ---------------------------------------------------------------------------
__global__ __launch_bounds__(256) void pack_weights(
    const float* __restrict__ Wf, const float* __restrict__ Wi,
    const float* __restrict__ Wg, const float* __restrict__ Wo,
    const float* __restrict__ ln_g, __hip_bfloat16* __restrict__ pack)
{
    __shared__ unsigned short tile[512 * 32];   // [k_local][c]
    const int blk = blockIdx.x;
    const int g = blk >> 1, part = blk & 1;
    const int tid = threadIdx.x;

    for (int idx = tid; idx < 512 * 32; idx += 256) {
        int kl = idx >> 5, c = idx & 31;
        int q = c >> 3, jl = c & 7;
        int k = part * 512 + kl;
        const float* W = (q == 0) ? Wf : ((q == 1) ? Wi : ((q == 2) ? Wg : Wo));
        float v = W[k * 512 + g * 8 + jl] * ln_g[k];
        tile[kl * 32 + c] = f2bf_bits(v);
    }
    __syncthreads();

    unsigned short* out = (unsigned short*)(pack + (size_t)blk * 16384);
    for (int s = tid; s < 2048; s += 256) {        // slot = tn*1024 + ks*64 + l
        int tn = s >> 10, ks = (s >> 6) & 15, l = s & 63;
        u16x8 v;
#pragma unroll
        for (int e = 0; e < 8; ++e) {
            int klocal = ks * 32 + ((l >> 4) * 8) + e;
            int c = tn * 16 + (l & 15);
            v[e] = tile[klocal * 32 + c];
        }
        *(u16x8*)(out + (size_t)s * 8) = v;
    }
}

// ---------------------------------------------------------------------------
// P2: S[n] = sum_k ln_g[k]*W[k,n],  C[n] = sum_k ln_b[k]*W[k,n] + bias[n]
// ---------------------------------------------------------------------------
__global__ __launch_bounds__(256) void compute_sc(
    const float* __restrict__ Wf, const float* __restrict__ Wi,
    const float* __restrict__ Wg, const float* __restrict__ Wo,
    const float* __restrict__ bf_, const float* __restrict__ bi_,
    const float* __restrict__ bg_, const float* __restrict__ bo_,
    const float* __restrict__ ln_g, const float* __restrict__ ln_b,
    float* __restrict__ S, float* __restrict__ C)
{
    int n = blockIdx.x * 256 + threadIdx.x;        // 0..2047
    int q = n >> 9, j = n & 511;
    const float* W = (q == 0) ? Wf : ((q == 1) ? Wi : ((q == 2) ? Wg : Wo));
    const float* bb = (q == 0) ? bf_ : ((q == 1) ? bi_ : ((q == 2) ? bg_ : bo_));
    float accS = 0.f, accC = 0.f;
    for (int k = 0; k < 1024; ++k) {
        float w = W[k * 512 + j];
        accS += ln_g[k] * w;
        accC += ln_b[k] * w;
    }
    S[n] = accS;
    C[n] = accC + bb[j];
}

// ---------------------------------------------------------------------------
// P3: x -> bf16 copy + per-row sum / sumsq (fp32). One wave per (t,b) row.
// ---------------------------------------------------------------------------
__global__ __launch_bounds__(256) void prep_x(
    const float* __restrict__ x, __hip_bfloat16* __restrict__ xb,
    float* __restrict__ sx, float* __restrict__ sq)
{
    const int wave = threadIdx.x >> 6, lane = threadIdx.x & 63;
    const long row = (long)blockIdx.x * 4 + wave;  // 0..65535
    const float* src = x + row * 512 + lane * 8;
    float4 a = *(const float4*)src;
    float4 b = *(const float4*)(src + 4);
    float vals[8] = {a.x, a.y, a.z, a.w, b.x, b.y, b.z, b.w};
    u16x8 o;
    float s = 0.f, qq = 0.f;
#pragma unroll
    for (int e = 0; e < 8; ++e) {
        s += vals[e];
        qq += vals[e] * vals[e];
        o[e] = f2bf_bits(vals[e]);
    }
    *(u16x8*)((unsigned short*)xb + row * 512 + lane * 8) = o;
#pragma unroll
    for (int d = 1; d < 64; d <<= 1) {
        s  += __shfl_xor(s, d);
        qq += __shfl_xor(qq, d);
    }
    if (lane == 0) { sx[row] = s; sq[row] = qq; }
}

// ---------------------------------------------------------------------------
// Main persistent kernel: 64 WGs x 512 threads.
// Wave w: m = w>>1 (16-row M tile), kh = w&1 (K half).
// Per-(WG,wave) flags: wave w of WG g publishes rows [w*8,w*8+8) of h and psc
// with sc1 relaxed stores + vmcnt(0) + relaxed flag store (NO wbl2 anywhere).
// Consumer wave (m,kh) polls flags (WG=lane, waves {2m,2m+1}) with one 8B
// agent load per lane: those two waves produce exactly the h rows and psc
// rows this wave consumes.
// Thread t: b = t>>3, jl = t&7 owns gate/state element (b, 8g+jl).
// ---------------------------------------------------------------------------
__global__ __launch_bounds__(512, 2) void qlstm_main(
    const float* __restrict__ x,
    const __hip_bfloat16* __restrict__ pack,
    const float* __restrict__ Sarr, const float* __restrict__ Carr,
    const __hip_bfloat16* __restrict__ xb,
    const float* __restrict__ sx, const float* __restrict__ sq,
    __hip_bfloat16* __restrict__ hxb,     // [2][64][512] bf16 (zeroed)
    float2* __restrict__ psc,             // [2][64][64] float2 (zeroed)
    unsigned int* __restrict__ flags,     // [64 WG][16 u32] = 64B/WG (zeroed)
    float* __restrict__ out)              // stacked | hx | cx (fp32)
{
    const int g = blockIdx.x;
    const int tid = threadIdx.x;
    const int wave = tid >> 6, lane = tid & 63;
    const int m = wave >> 1, kh = wave & 1;
    const int b = tid >> 3, jl = tid & 7, jg = g * 8 + jl;

    __shared__ float zXs[2][2][2112];          // [parity][kh][row*33+col]
    __shared__ float zHs[2][2112];             // [kh]
    __shared__ float Scol[32], Ccol[32];

    if (tid < 32) {
        int n = (tid >> 3) * 512 + g * 8 + (tid & 7);
        Scol[tid] = Sarr[n];
        Ccol[tid] = Carr[n];
    }

    // Persistent B-fragments: 4 x 8 frags x 4 VGPR = 128 VGPRs.
    bf16x8 Bx0[8], Bx1[8], Bh0[8], Bh1[8];
    {
        const bf16x8* px = (const bf16x8*)(pack + (size_t)(g * 2 + 0) * 16384);
        const bf16x8* ph = (const bf16x8*)(pack + (size_t)(g * 2 + 1) * 16384);
#pragma unroll
        for (int i = 0; i < 8; ++i) {
            int ksp = kh * 8 + i;
            Bx0[i] = px[ksp * 64 + lane];
            Bx1[i] = px[1024 + ksp * 64 + lane];
            Bh0[i] = ph[ksp * 64 + lane];
            Bh1[i] = ph[1024 + ksp * 64 + lane];
        }
    }

    const int arow = m * 16 + (lane & 15);
    const int acol = (lane >> 4) * 8;
    const int r0 = m * 16 + (lane >> 4) * 4, c0 = lane & 15;
    float cx = 0.f;

    // zX for t=0 (x-part GEMM, recurrence-independent)
    {
        const bf16x8* Ap = (const bf16x8*)(xb + (size_t)arow * 512 + kh * 256 + acol);
        bf16x8 afr[8];
#pragma unroll
        for (int ks = 0; ks < 8; ++ks) afr[ks] = Ap[ks * 4];
        f32x4 a0 = {0.f, 0.f, 0.f, 0.f}, a1 = {0.f, 0.f, 0.f, 0.f};
#pragma unroll
        for (int ks = 0; ks < 8; ++ks) {
            a0 = __builtin_amdgcn_mfma_f32_16x16x32_bf16(afr[ks], Bx0[ks], a0, 0, 0, 0);
            a1 = __builtin_amdgcn_mfma_f32_16x16x32_bf16(afr[ks], Bx1[ks], a1, 0, 0, 0);
        }
        float* zb = &zXs[0][kh][0];
#pragma unroll
        for (int r = 0; r < 4; ++r) {
            zb[(r0 + r) * 33 + c0]      = a0[r];
            zb[(r0 + r) * 33 + 16 + c0] = a1[r];
        }
    }

    for (int t = 0; t < T_STEPS; ++t) {
        const int p = t & 1;

        // recurrence-independent loads: issue before the spin
        float xres = x[(size_t)t * 32768 + b * 512 + jg];
        float sxv = sx[t * 64 + b];
        float sqv = sq[t * 64 + b];

        // ---- spin: lane l polls waves {2m,2m+1} of WG l (one 8B load) ----
        if (t) {
            const unsigned long long* fp_ =
                (const unsigned long long*)(flags + lane * 16 + m * 2);
            for (;;) {
                unsigned long long v = __hip_atomic_load(fp_, __ATOMIC_RELAXED,
                                                         __HIP_MEMORY_SCOPE_AGENT);
                unsigned fa = (unsigned)v, fb = (unsigned)(v >> 32);
                unsigned mn = fa < fb ? fa : fb;
                if (__all((int)mn >= t)) break;
            }
            asm volatile("" ::: "memory");
        }

        // ---- coherent h A-frag loads (16 x 8B per lane) ----
        unsigned long long hlo[8], hhi[8];
        {
            const unsigned long long* hp =
                (const unsigned long long*)(hxb + (size_t)p * 32768);
            const int ebase = (arow * 512 + kh * 256 + acol) >> 2;
#pragma unroll
            for (int ks = 0; ks < 8; ++ks) {
                hlo[ks] = __hip_atomic_load(hp + ebase + ks * 8, __ATOMIC_RELAXED,
                                            __HIP_MEMORY_SCOPE_AGENT);
                hhi[ks] = __hip_atomic_load(hp + ebase + ks * 8 + 1, __ATOMIC_RELAXED,
                                            __HIP_MEMORY_SCOPE_AGENT);
            }
        }

        // ---- coherent psc loads -> register partials (overlap h loads) ----
        float s1 = 0.f, s2 = 0.f;
        {
            const unsigned long long* pp =
                (const unsigned long long*)(psc + (size_t)p * 4096 + b * 64 + jl * 8);
#pragma unroll
            for (int j = 0; j < 8; ++j) {
                unsigned long long v = __hip_atomic_load(pp + j, __ATOMIC_RELAXED,
                                                         __HIP_MEMORY_SCOPE_AGENT);
                union { unsigned long long u; float2 f; } cv; cv.u = v;
                s1 += cv.f.x; s2 += cv.f.y;
            }
        }

        // ---- h-GEMM (critical path): 16 MFMA per wave ----
        {
            f32x4 h0 = {0.f, 0.f, 0.f, 0.f}, h1 = {0.f, 0.f, 0.f, 0.f};
#pragma unroll
            for (int ks = 0; ks < 8; ++ks) {
                union { unsigned long long u[2]; bf16x8 v; } cv;
                cv.u[0] = hlo[ks]; cv.u[1] = hhi[ks];
                h0 = __builtin_amdgcn_mfma_f32_16x16x32_bf16(cv.v, Bh0[ks], h0, 0, 0, 0);
                h1 = __builtin_amdgcn_mfma_f32_16x16x32_bf16(cv.v, Bh1[ks], h1, 0, 0, 0);
            }
            float* zb = &zHs[kh][0];
#pragma unroll
            for (int r = 0; r < 4; ++r) {
                zb[(r0 + r) * 33 + c0]      = h0[r];
                zb[(r0 + r) * 33 + 16 + c0] = h1[r];
            }
        }
        __syncthreads();

        // ---- gates / state update (thread owns (b, jg)) ----
        float hval;
        {
            float hs = s1, hq = s2;
            hs += __shfl_xor(hs, 1, 8); hq += __shfl_xor(hq, 1, 8);
            hs += __shfl_xor(hs, 2, 8); hq += __shfl_xor(hq, 2, 8);
            hs += __shfl_xor(hs, 4, 8); hq += __shfl_xor(hq, 4, 8);
            float mu = (sxv + hs) * (1.f / 1024.f);
            float var = (sqv + hq) * (1.f / 1024.f) - mu * mu;
            float rs = rsqrtf(var + 1e-5f);

            const float* zx0 = &zXs[p][0][0];
            const float* zx1 = &zXs[p][1][0];
            const float* zh0 = &zHs[0][0];
            const float* zh1 = &zHs[1][0];
            const int i0 = b * 33;
            float zf = zx0[i0 + jl]      + zx1[i0 + jl]      + zh0[i0 + jl]      + zh1[i0 + jl];
            float zi = zx0[i0 + 8 + jl]  + zx1[i0 + 8 + jl]  + zh0[i0 + 8 + jl]  + zh1[i0 + 8 + jl];
            float zg = zx0[i0 + 16 + jl] + zx1[i0 + 16 + jl] + zh0[i0 + 16 + jl] + zh1[i0 + 16 + jl];
            float zo = zx0[i0 + 24 + jl] + zx1[i0 + 24 + jl] + zh0[i0 + 24 + jl] + zh1[i0 + 24 + jl];
            zf = rs * (zf - mu * Scol[jl])      + Ccol[jl];
            zi = rs * (zi - mu * Scol[8 + jl])  + Ccol[8 + jl];
            zg = rs * (zg - mu * Scol[16 + jl]) + Ccol[16 + jl];
            zo = rs * (zo - mu * Scol[24 + jl]) + Ccol[24 + jl];

            float f  = 1.f / (1.f + __expf(-zf));
            float i_ = 1.f / (1.f + __expf(-zi));
            float gg = 2.f / (1.f + __expf(-2.f * zg)) - 1.f;
            float o_ = 1.f / (1.f + __expf(-2.f * -zo * -1.f)); // placeholder avoided below
            o_ = 1.f / (1.f + __expf(-zo));
            cx = f * cx + i_ * gg;
            float th = 2.f / (1.f + __expf(-2.f * cx)) - 1.f;
            hval = o_ * th + xres;
        }

        // ---- publish (sc1 write-through, straight from registers) ----
        if (t + 1 < T_STEPS) {
            unsigned hb = (unsigned)f2bf_bits(hval);
            unsigned v01 = hb | ((unsigned)__shfl_xor((int)hb, 1) << 16);
            unsigned long long v03 = (unsigned long long)v01 |
                ((unsigned long long)(unsigned)__shfl_xor((int)v01, 2) << 32);
            if ((jl & 3) == 0) {
                unsigned long long* hdst = (unsigned long long*)
                    ((unsigned short*)hxb + (size_t)(p ^ 1) * 32768 + b * 512 + g * 8 + jl);
                __hip_atomic_store(hdst, v03, __ATOMIC_RELAXED, __HIP_MEMORY_SCOPE_AGENT);
            }
            float p1 = hval, p2 = hval * hval;
            p1 += __shfl_xor(p1, 1, 8); p2 += __shfl_xor(p2, 1, 8);
            p1 += __shfl_xor(p1, 2, 8); p2 += __shfl_xor(p2, 2, 8);
            p1 += __shfl_xor(p1, 4, 8); p2 += __shfl_xor(p2, 4, 8);
            if (jl == 0) {
                union { float2 f; unsigned long long u; } cv;
                cv.f = make_float2(p1, p2);
                __hip_atomic_store((unsigned long long*)
                    (psc + (size_t)(p ^ 1) * 4096 + b * 64 + g),
                    cv.u, __ATOMIC_RELAXED, __HIP_MEMORY_SCOPE_AGENT);
            }
            asm volatile("s_waitcnt vmcnt(0)" ::: "memory");
            if (lane == 0) {
                __hip_atomic_store(flags + g * 16 + wave, (unsigned)(t + 1),
                                   __ATOMIC_RELAXED, __HIP_MEMORY_SCOPE_AGENT);
            }
        }

        // ---- shadow work: out writes ----
        out[(size_t)t * 32768 + b * 512 + jg] = hval;
        if (t == T_STEPS - 1) {
            out[(size_t)T_STEPS * 32768 + b * 512 + jg] = hval;
            out[(size_t)T_STEPS * 32768 + 32768 + b * 512 + jg] = cx;
        }

        __syncthreads();   // zHs/zXs reuse guard

        // ---- x-GEMM for t+1 (off critical path) ----
        if (t + 1 < T_STEPS) {
            const bf16x8* Ap = (const bf16x8*)(xb + (size_t)(t + 1) * 32768
                                               + arow * 512 + kh * 256 + acol);
            bf16x8 afr[8];
#pragma unroll
            for (int ks = 0; ks < 8; ++ks) afr[ks] = Ap[ks * 4];
            f32x4 a0 = {0.f, 0.f, 0.f, 0.f}, a1 = {0.f, 0.f, 0.f, 0.f};
#pragma unroll
            for (int ks = 0; ks < 8; ++ks) {
                a0 = __builtin_amdgcn_mfma_f32_16x16x32_bf16(afr[ks], Bx0[ks], a0, 0, 0, 0);
                a1 = __builtin_amdgcn_mfma_f32_16x16x32_bf16(afr[ks], Bx1[ks], a1, 0, 0, 0);
            }
            float* zb = &zXs[p ^ 1][kh][0];
#pragma unroll
            for (int r = 0; r < 4; ++r) {
                zb[(r0 + r) * 33 + c0]      = a0[r];
                zb[(r0 + r) * 33 + 16 + c0] = a1[r];
            }
        }
    }
}

// ---------------------------------------------------------------------------
extern "C" void kernel_launch(void* const* d_in, const int* in_sizes, int n_in,
                              void* d_out, int out_size, void* d_ws, size_t ws_size,
                              hipStream_t stream)
{
    const float* x    = (const float*)d_in[0];
    const float* ln_g = (const float*)d_in[1];
    const float* ln_b = (const float*)d_in[2];
    const float* Wf   = (const float*)d_in[3];
    const float* bf_  = (const float*)d_in[4];
    const float* Wi   = (const float*)d_in[5];
    const float* bi_  = (const float*)d_in[6];
    const float* Wg   = (const float*)d_in[7];
    const float* bg_  = (const float*)d_in[8];
    const float* Wo   = (const float*)d_in[9];
    const float* bo_  = (const float*)d_in[10];

    char* ws = (char*)d_ws;
    size_t off = 0;
    auto take = [&](size_t bytes) -> char* {
        char* p = ws + off;
        off += (bytes + 255) & ~(size_t)255;
        return p;
    };
    __hip_bfloat16* pack = (__hip_bfloat16*)take((size_t)2097152 * 2); // 4 MB
    float* S             = (float*)take(2048 * 4);
    float* C             = (float*)take(2048 * 4);
    __hip_bfloat16* xb   = (__hip_bfloat16*)take((size_t)33554432 * 2); // 64 MB
    float* sx            = (float*)take(65536 * 4);
    float* sq            = (float*)take(65536 * 4);
    char* ctrl = ws + off;
    __hip_bfloat16* hxb  = (__hip_bfloat16*)take((size_t)2 * 64 * 512 * 2);
    float2* psc          = (float2*)take((size_t)2 * 64 * 64 * 8);
    unsigned int* flags  = (unsigned int*)take(64 * 64);
    size_t ctrl_bytes = (size_t)((ws + off) - ctrl);

    hipMemsetAsync(ctrl, 0, ctrl_bytes, stream);
    pack_weights<<<dim3(128), dim3(256), 0, stream>>>(Wf, Wi, Wg, Wo, ln_g, pack);
    compute_sc<<<dim3(8), dim3(256), 0, stream>>>(Wf, Wi, Wg, Wo, bf_, bi_, bg_, bo_,
                                                  ln_g, ln_b, S, C);
    prep_x<<<dim3(16384), dim3(256), 0, stream>>>(x, xb, sx, sq);
    qlstm_main<<<dim3(NWG), dim3(512), 0, stream>>>(x, pack, S, C, xb, sx, sq,
                                                    hxb, psc, flags, (float*)d_out);
}